// Round 1
// baseline (1539.911 us; speedup 1.0000x reference)
//
#include <hip/hip_runtime.h>
#include <hip/hip_bf16.h>

// GCN forward: out = spmm(A, relu(spmm(A, x@W1)+b1) @ W2) + b2
// A given as COO (edge_row, edge_col, edge_val), E=1.7M, N=100K.
// Strategy: build CSR on device each call, dense GEMMs + row-parallel SpMM.

#define NFEATS 512
#define NHIDS  256
#define NCLS   40

// ---------------- CSR build ----------------

__global__ void hist_kernel(const int* __restrict__ row, int* __restrict__ cnt, int E) {
    int e = blockIdx.x * blockDim.x + threadIdx.x;
    if (e < E) atomicAdd(&cnt[row[e]], 1);
}

// Single-block chunked exclusive scan over N counts -> row_ptr[N+1]; zeroes cnt for reuse as fill.
#define SCAN_T 1024
__global__ __launch_bounds__(SCAN_T) void scan_kernel(int* __restrict__ cnt, int* __restrict__ row_ptr, int N) {
    __shared__ int s[SCAN_T];
    int t = threadIdx.x;
    int per = (N + SCAN_T - 1) / SCAN_T;
    int begin = t * per;
    int end = begin + per; if (end > N) end = N;
    int sum = 0;
    for (int i = begin; i < end; i++) sum += cnt[i];
    s[t] = sum;
    __syncthreads();
    // Hillis-Steele inclusive scan
    for (int off = 1; off < SCAN_T; off <<= 1) {
        int x = (t >= off) ? s[t - off] : 0;
        __syncthreads();
        s[t] += x;
        __syncthreads();
    }
    int run = s[t] - sum;  // exclusive prefix
    for (int i = begin; i < end; i++) {
        int c = cnt[i];
        row_ptr[i] = run;
        run += c;
        cnt[i] = 0;  // reuse as fill counter in scatter
    }
    if (t == SCAN_T - 1) row_ptr[N] = run;  // == E
}

__global__ void scatter_kernel(const int* __restrict__ row, const int* __restrict__ col,
                               const float* __restrict__ val, const int* __restrict__ row_ptr,
                               int* __restrict__ fill, int* __restrict__ csr_col,
                               float* __restrict__ csr_val, int E) {
    int e = blockIdx.x * blockDim.x + threadIdx.x;
    if (e < E) {
        int r = row[e];
        int p = row_ptr[r] + atomicAdd(&fill[r], 1);
        csr_col[p] = col[e];
        csr_val[p] = val[e];
    }
}

// ---------------- GEMM1: H1 = x @ W1  (M x 512) @ (512 x 256) ----------------
// 64x64 tile, BK=16, 256 threads, 4x4 microtile.

#define BM 64
#define BN 64
#define BK 16

__global__ __launch_bounds__(256) void gemm1_kernel(const float* __restrict__ A,
                                                    const float* __restrict__ B,
                                                    float* __restrict__ C, int M) {
    __shared__ float As[BK][BM + 4];  // transposed, +4 pad keeps 16B alignment & breaks stride
    __shared__ float Bs[BK][BN];
    const int K = NFEATS, Ncol = NHIDS;
    int tid = threadIdx.x;
    int tx = tid % 16, ty = tid / 16;
    int m0 = blockIdx.x * BM;
    int n0 = blockIdx.y * BN;

    int a_m  = tid / 4;        // 0..63
    int a_k4 = (tid % 4) * 4;  // 0,4,8,12
    int b_k  = tid / 16;       // 0..15
    int b_n4 = (tid % 16) * 4; // 0..60

    float acc[4][4] = {};

    for (int k0 = 0; k0 < K; k0 += BK) {
        float4 av = make_float4(0.f, 0.f, 0.f, 0.f);
        int arow = m0 + a_m;
        if (arow < M) av = *(const float4*)(A + (size_t)arow * K + k0 + a_k4);
        As[a_k4 + 0][a_m] = av.x;
        As[a_k4 + 1][a_m] = av.y;
        As[a_k4 + 2][a_m] = av.z;
        As[a_k4 + 3][a_m] = av.w;
        float4 bv = *(const float4*)(B + (size_t)(k0 + b_k) * Ncol + n0 + b_n4);
        *(float4*)&Bs[b_k][b_n4] = bv;
        __syncthreads();
#pragma unroll
        for (int k = 0; k < BK; k++) {
            float4 a = *(const float4*)&As[k][ty * 4];
            float4 b = *(const float4*)&Bs[k][tx * 4];
            acc[0][0] += a.x * b.x; acc[0][1] += a.x * b.y; acc[0][2] += a.x * b.z; acc[0][3] += a.x * b.w;
            acc[1][0] += a.y * b.x; acc[1][1] += a.y * b.y; acc[1][2] += a.y * b.z; acc[1][3] += a.y * b.w;
            acc[2][0] += a.z * b.x; acc[2][1] += a.z * b.y; acc[2][2] += a.z * b.z; acc[2][3] += a.z * b.w;
            acc[3][0] += a.w * b.x; acc[3][1] += a.w * b.y; acc[3][2] += a.w * b.z; acc[3][3] += a.w * b.w;
        }
        __syncthreads();
    }
#pragma unroll
    for (int i = 0; i < 4; i++) {
        int row = m0 + ty * 4 + i;
        if (row < M) {
            *(float4*)(C + (size_t)row * Ncol + n0 + tx * 4) =
                make_float4(acc[i][0], acc[i][1], acc[i][2], acc[i][3]);
        }
    }
}

// ---------------- SpMM1: AGG[r] = relu(sum_e val*H1[col] + b1), F=256 ----------------
// one block (256 threads) per row; thread = feature. csr_col[j] is wave-uniform -> s_load.

__global__ __launch_bounds__(256) void spmm1_kernel(const int* __restrict__ row_ptr,
                                                    const int* __restrict__ csr_col,
                                                    const float* __restrict__ csr_val,
                                                    const float* __restrict__ H1,
                                                    const float* __restrict__ b1,
                                                    float* __restrict__ AGG) {
    int r = blockIdx.x;
    int f = threadIdx.x;
    int s = row_ptr[r], e = row_ptr[r + 1];
    float acc = 0.f;
    for (int j = s; j < e; j++) {
        int c = csr_col[j];
        float v = csr_val[j];
        acc += v * H1[(size_t)c * NHIDS + f];
    }
    float h = acc + b1[f];
    AGG[(size_t)r * NHIDS + f] = h > 0.f ? h : 0.f;
}

// ---------------- GEMM2: H2 = AGG @ W2  (M x 256) @ (256 x 40) ----------------
// thread per row; W2 indices are uniform -> compiler scalarizes to s_load (SGPR operands).

__global__ __launch_bounds__(256) void gemm2_kernel(const float* __restrict__ H,
                                                    const float* __restrict__ W2,
                                                    float* __restrict__ H2, int M) {
    int row = blockIdx.x * blockDim.x + threadIdx.x;
    if (row >= M) return;
    const float* hrow = H + (size_t)row * NHIDS;
    float acc[NCLS] = {};
    for (int k4 = 0; k4 < NHIDS; k4 += 4) {
        float4 a = *(const float4*)(hrow + k4);
#pragma unroll
        for (int j = 0; j < NCLS; j++) {
            acc[j] += a.x * W2[(k4 + 0) * NCLS + j];
            acc[j] += a.y * W2[(k4 + 1) * NCLS + j];
            acc[j] += a.z * W2[(k4 + 2) * NCLS + j];
            acc[j] += a.w * W2[(k4 + 3) * NCLS + j];
        }
    }
    float* o = H2 + (size_t)row * NCLS;
#pragma unroll
    for (int j = 0; j < NCLS; j++) o[j] = acc[j];
}

// ---------------- SpMM2: out[r] = sum_e val*H2[col] + b2, F=40 ----------------

__global__ __launch_bounds__(64) void spmm2_kernel(const int* __restrict__ row_ptr,
                                                   const int* __restrict__ csr_col,
                                                   const float* __restrict__ csr_val,
                                                   const float* __restrict__ H2,
                                                   const float* __restrict__ b2,
                                                   float* __restrict__ out) {
    int r = blockIdx.x;
    int f = threadIdx.x;
    if (f >= NCLS) return;
    int s = row_ptr[r], e = row_ptr[r + 1];
    float acc = 0.f;
    for (int j = s; j < e; j++) {
        acc += csr_val[j] * H2[(size_t)csr_col[j] * NCLS + f];
    }
    out[(size_t)r * NCLS + f] = acc + b2[f];
}

// ---------------- launch ----------------

static inline size_t align16(size_t x) { return (x + 15) & ~(size_t)15; }

extern "C" void kernel_launch(void* const* d_in, const int* in_sizes, int n_in,
                              void* d_out, int out_size, void* d_ws, size_t ws_size,
                              hipStream_t stream) {
    const float* x        = (const float*)d_in[0];
    const float* W1       = (const float*)d_in[1];
    const float* b1       = (const float*)d_in[2];
    const float* W2       = (const float*)d_in[3];
    const float* b2       = (const float*)d_in[4];
    const int*   edge_row = (const int*)d_in[5];
    const int*   edge_col = (const int*)d_in[6];
    const float* edge_val = (const float*)d_in[7];
    float* out = (float*)d_out;

    int N = in_sizes[0] / NFEATS;  // 100000
    int E = in_sizes[5];           // 1700000

    // workspace carve-up
    char* w = (char*)d_ws;
    size_t off = 0;
    float* H1 = (float*)(w + off); off += align16((size_t)N * NHIDS * 4);
    float* AGG = (float*)(w + off); off += align16((size_t)N * NHIDS * 4);
    int* row_ptr = (int*)(w + off); off += align16((size_t)(N + 1) * 4);
    int* cnt = (int*)(w + off); off += align16((size_t)N * 4);
    int* csr_col = (int*)(w + off); off += align16((size_t)E * 4);
    float* csr_val = (float*)(w + off); off += align16((size_t)E * 4);
    float* H2 = H1;  // H1 dead after spmm1 -> reuse region for H2 (N x 40)

    // CSR build
    hipMemsetAsync(cnt, 0, (size_t)N * 4, stream);
    hist_kernel<<<(E + 255) / 256, 256, 0, stream>>>(edge_row, cnt, E);
    scan_kernel<<<1, SCAN_T, 0, stream>>>(cnt, row_ptr, N);
    scatter_kernel<<<(E + 255) / 256, 256, 0, stream>>>(edge_row, edge_col, edge_val,
                                                        row_ptr, cnt, csr_col, csr_val, E);

    // layer 1
    gemm1_kernel<<<dim3((N + BM - 1) / BM, NHIDS / BN), 256, 0, stream>>>(x, W1, H1, N);
    spmm1_kernel<<<N, 256, 0, stream>>>(row_ptr, csr_col, csr_val, H1, b1, AGG);

    // layer 2
    gemm2_kernel<<<(N + 255) / 256, 256, 0, stream>>>(AGG, W2, H2, N);
    spmm2_kernel<<<N, 64, 0, stream>>>(row_ptr, csr_col, csr_val, H2, b2, out);
}

// Round 3
// 1160.503 us; speedup vs baseline: 1.3269x; 1.3269x over previous
//
#include <hip/hip_runtime.h>
#include <hip/hip_bf16.h>

// GCN forward: out = spmm(A, relu(spmm(A, x@W1)+b1) @ W2) + b2
// bf16 intermediate pipeline: GEMM1 via MFMA bf16, H1/AGG/H2 stored bf16.
// R3 fix: gemm1 B-staging needs 4 rounds (1024x16B), not 2 — rows 128..255
// of Bs were stale in R2 (absmax 0.345).

#define NFEATS 512
#define NHIDS  256
#define NCLS   40
#define NCLSP  64   // H2 padded feature stride (one 128B line per row)

typedef unsigned short ushort_t;
typedef unsigned int uint_t;
typedef __attribute__((ext_vector_type(8))) short frag8;   // 8 bf16 = 16 B
typedef __attribute__((ext_vector_type(4))) float floatx4;

__device__ __forceinline__ ushort_t f2b(float f) {
    uint_t u = __float_as_uint(f);
    uint_t r = (u + 0x7fffu + ((u >> 16) & 1u)) >> 16;   // RNE
    return (ushort_t)r;
}
__device__ __forceinline__ float b2f(ushort_t b) {
    return __uint_as_float((uint_t)b << 16);
}

// ---------------- CSR build ----------------

__global__ void hist_kernel(const int* __restrict__ row, int* __restrict__ cnt, int E) {
    int e = blockIdx.x * blockDim.x + threadIdx.x;
    if (e < E) atomicAdd(&cnt[row[e]], 1);
}

#define SCAN_T 1024
__global__ __launch_bounds__(SCAN_T) void scan_kernel(int* __restrict__ cnt, int* __restrict__ row_ptr, int N) {
    __shared__ int s[SCAN_T];
    int t = threadIdx.x;
    int per = (N + SCAN_T - 1) / SCAN_T;
    int begin = t * per;
    int end = begin + per; if (end > N) end = N;
    int sum = 0;
    for (int i = begin; i < end; i++) sum += cnt[i];
    s[t] = sum;
    __syncthreads();
    for (int off = 1; off < SCAN_T; off <<= 1) {
        int x = (t >= off) ? s[t - off] : 0;
        __syncthreads();
        s[t] += x;
        __syncthreads();
    }
    int run = s[t] - sum;
    for (int i = begin; i < end; i++) {
        int c = cnt[i];
        row_ptr[i] = run;
        run += c;
        cnt[i] = 0;
    }
    if (t == SCAN_T - 1) row_ptr[N] = run;
}

__global__ void scatter_kernel(const int* __restrict__ row, const int* __restrict__ col,
                               const float* __restrict__ val, const int* __restrict__ row_ptr,
                               int* __restrict__ fill, int2* __restrict__ cv, int E) {
    int e = blockIdx.x * blockDim.x + threadIdx.x;
    if (e < E) {
        int r = row[e];
        int p = row_ptr[r] + atomicAdd(&fill[r], 1);
        cv[p] = make_int2(col[e], __float_as_int(val[e]));
    }
}

// ---------------- W1 convert+transpose: [512][256] f32 -> [256][512] bf16 ----------------

__global__ void convert_w1(const float* __restrict__ W1, ushort_t* __restrict__ W1t) {
    int idx = blockIdx.x * 256 + threadIdx.x;   // 131072 total
    int k = idx >> 8, n = idx & 255;
    W1t[n * 512 + k] = f2b(W1[idx]);
}

// ---------------- GEMM1: H1 = bf16(x @ W1)  via MFMA ----------------
// tile 64(M) x 256(N), BK=32, 256 threads = 4 waves; wave w covers n = w*64..w*64+63.
// Each wave: 4x4 grid of 16x16x32 MFMAs.

#define G1_BM 64
#define G1_BN 256
#define G1_BK 32
#define LDK   40   // padded K-stride (elements); 80 B, 16B-aligned, conflict-free b128 reads

__global__ __launch_bounds__(256) void gemm1_kernel(const float* __restrict__ A,
                                                    const ushort_t* __restrict__ Bt,
                                                    ushort_t* __restrict__ H1, int M) {
    __shared__ ushort_t As[G1_BM * LDK];   // 5120 B
    __shared__ ushort_t Bs[G1_BN * LDK];   // 20480 B
    int tid  = threadIdx.x;
    int wave = tid >> 6, lane = tid & 63;
    int quad = lane >> 4, ln = lane & 15;
    int m0 = blockIdx.x * G1_BM;

    floatx4 acc[4][4] = {};

    for (int k0 = 0; k0 < NFEATS; k0 += G1_BK) {
        // stage A (fp32 -> bf16): 64 rows x 32 k = 512 float4 loads, 2 rounds
#pragma unroll
        for (int i = 0; i < 2; i++) {
            int idx = i * 256 + tid;
            int row = idx >> 3;
            int c4  = idx & 7;
            float4 v = make_float4(0.f, 0.f, 0.f, 0.f);
            int gr = m0 + row;
            if (gr < M) v = *(const float4*)(A + (size_t)gr * NFEATS + k0 + c4 * 4);
            ushort4 b;
            b.x = f2b(v.x); b.y = f2b(v.y); b.z = f2b(v.z); b.w = f2b(v.w);
            *(ushort4*)&As[row * LDK + c4 * 4] = b;
        }
        // stage B (already bf16, n-major): 256 n x 4 k-chunks(8 bf16) = 1024 x 16B, 4 rounds
#pragma unroll
        for (int i = 0; i < 4; i++) {
            int idx = i * 256 + tid;
            int n  = idx >> 2;
            int k8 = idx & 3;
            uint4 v = *(const uint4*)(Bt + (size_t)n * 512 + k0 + k8 * 8);
            *(uint4*)&Bs[n * LDK + k8 * 8] = v;
        }
        __syncthreads();
        frag8 af[4], bf[4];
#pragma unroll
        for (int t = 0; t < 4; t++)
            af[t] = *(const frag8*)&As[(t * 16 + ln) * LDK + quad * 8];
#pragma unroll
        for (int t = 0; t < 4; t++)
            bf[t] = *(const frag8*)&Bs[(wave * 64 + t * 16 + ln) * LDK + quad * 8];
#pragma unroll
        for (int mt = 0; mt < 4; mt++)
#pragma unroll
            for (int nt = 0; nt < 4; nt++)
                acc[mt][nt] = __builtin_amdgcn_mfma_f32_16x16x32_bf16(af[mt], bf[nt], acc[mt][nt], 0, 0, 0);
        __syncthreads();
    }
    // C/D layout: col = lane&15, row = quad*4 + reg
#pragma unroll
    for (int mt = 0; mt < 4; mt++) {
#pragma unroll
        for (int i = 0; i < 4; i++) {
            int m = m0 + mt * 16 + quad * 4 + i;
            if (m < M) {
#pragma unroll
                for (int nt = 0; nt < 4; nt++) {
                    H1[(size_t)m * NHIDS + wave * 64 + nt * 16 + ln] = f2b(acc[mt][nt][i]);
                }
            }
        }
    }
}

// ---------------- SpMM1: AGG = bf16(relu(A_hat @ H1 + b1)), F=256 ----------------
// one wave per row; lane covers 4 feats (8 B); 2-edge unroll for MLP.

__global__ __launch_bounds__(256) void spmm1_kernel(const int* __restrict__ row_ptr,
                                                    const int2* __restrict__ cv,
                                                    const ushort_t* __restrict__ H1,
                                                    const float* __restrict__ b1,
                                                    ushort_t* __restrict__ AGG, int N) {
    int wave = threadIdx.x >> 6, lane = threadIdx.x & 63;
    int r = blockIdx.x * 4 + wave;
    if (r >= N) return;
    int s = row_ptr[r], e = row_ptr[r + 1];
    float a0 = 0.f, a1 = 0.f, a2 = 0.f, a3 = 0.f;
    int j = s;
    for (; j + 1 < e; j += 2) {
        int2 p0 = cv[j];
        int2 p1 = cv[j + 1];
        ushort4 h0 = *(const ushort4*)(H1 + (size_t)p0.x * NHIDS + lane * 4);
        ushort4 h1 = *(const ushort4*)(H1 + (size_t)p1.x * NHIDS + lane * 4);
        float v0 = __int_as_float(p0.y), v1 = __int_as_float(p1.y);
        a0 += v0 * b2f(h0.x); a1 += v0 * b2f(h0.y); a2 += v0 * b2f(h0.z); a3 += v0 * b2f(h0.w);
        a0 += v1 * b2f(h1.x); a1 += v1 * b2f(h1.y); a2 += v1 * b2f(h1.z); a3 += v1 * b2f(h1.w);
    }
    if (j < e) {
        int2 p0 = cv[j];
        ushort4 h0 = *(const ushort4*)(H1 + (size_t)p0.x * NHIDS + lane * 4);
        float v0 = __int_as_float(p0.y);
        a0 += v0 * b2f(h0.x); a1 += v0 * b2f(h0.y); a2 += v0 * b2f(h0.z); a3 += v0 * b2f(h0.w);
    }
    float4 bb = *(const float4*)(b1 + lane * 4);
    a0 += bb.x; a1 += bb.y; a2 += bb.z; a3 += bb.w;
    ushort4 o;
    o.x = f2b(a0 > 0.f ? a0 : 0.f);
    o.y = f2b(a1 > 0.f ? a1 : 0.f);
    o.z = f2b(a2 > 0.f ? a2 : 0.f);
    o.w = f2b(a3 > 0.f ? a3 : 0.f);
    *(ushort4*)&AGG[(size_t)r * NHIDS + lane * 4] = o;
}

// ---------------- GEMM2: H2 = bf16(AGG @ W2), padded to 64 cols ----------------

__global__ __launch_bounds__(256) void gemm2_kernel(const ushort_t* __restrict__ AGG,
                                                    const float* __restrict__ W2,
                                                    ushort_t* __restrict__ H2, int M) {
    int row = blockIdx.x * 256 + threadIdx.x;
    if (row >= M) return;
    const ushort_t* a = AGG + (size_t)row * NHIDS;
    float acc[NCLS] = {};
    for (int k0 = 0; k0 < NHIDS; k0 += 8) {
        uint4 av = *(const uint4*)(a + k0);
        float f0 = b2f((ushort_t)(av.x & 0xffff)), f1 = b2f((ushort_t)(av.x >> 16));
        float f2 = b2f((ushort_t)(av.y & 0xffff)), f3 = b2f((ushort_t)(av.y >> 16));
        float f4 = b2f((ushort_t)(av.z & 0xffff)), f5 = b2f((ushort_t)(av.z >> 16));
        float f6 = b2f((ushort_t)(av.w & 0xffff)), f7 = b2f((ushort_t)(av.w >> 16));
#pragma unroll
        for (int jj = 0; jj < NCLS; jj++) {
            acc[jj] += f0 * W2[(k0 + 0) * NCLS + jj];
            acc[jj] += f1 * W2[(k0 + 1) * NCLS + jj];
            acc[jj] += f2 * W2[(k0 + 2) * NCLS + jj];
            acc[jj] += f3 * W2[(k0 + 3) * NCLS + jj];
            acc[jj] += f4 * W2[(k0 + 4) * NCLS + jj];
            acc[jj] += f5 * W2[(k0 + 5) * NCLS + jj];
            acc[jj] += f6 * W2[(k0 + 6) * NCLS + jj];
            acc[jj] += f7 * W2[(k0 + 7) * NCLS + jj];
        }
    }
    // pack 40 bf16 + 24 zero-pad into 8 uint4 stores
    uint_t packed[NCLSP / 2];
#pragma unroll
    for (int jj = 0; jj < NCLS / 2; jj++)
        packed[jj] = (uint_t)f2b(acc[2 * jj]) | ((uint_t)f2b(acc[2 * jj + 1]) << 16);
#pragma unroll
    for (int jj = NCLS / 2; jj < NCLSP / 2; jj++) packed[jj] = 0;
    uint_t* o = (uint_t*)(H2 + (size_t)row * NCLSP);
#pragma unroll
    for (int q = 0; q < NCLSP / 8; q++)
        *(uint4*)(o + q * 4) = make_uint4(packed[q * 4], packed[q * 4 + 1], packed[q * 4 + 2], packed[q * 4 + 3]);
}

// ---------------- SpMM2: out = A_hat @ H2 + b2, F=40 (padded reads of 64) ----------------
// half-wave (32 lanes) per row; lane reads one uint = 2 bf16; whole padded row = one 128B line.

__global__ __launch_bounds__(256) void spmm2_kernel(const int* __restrict__ row_ptr,
                                                    const int2* __restrict__ cv,
                                                    const ushort_t* __restrict__ H2,
                                                    const float* __restrict__ b2,
                                                    float* __restrict__ out, int N) {
    int wave = threadIdx.x >> 6, lane = threadIdx.x & 63;
    int half = lane >> 5, fl = lane & 31;
    int r = blockIdx.x * 8 + wave * 2 + half;
    if (r >= N) return;
    int s = row_ptr[r], e = row_ptr[r + 1];
    float a0 = 0.f, a1 = 0.f;
    for (int j = s; j < e; j++) {
        int2 p = cv[j];
        float v = __int_as_float(p.y);
        uint_t h = *(const uint_t*)(H2 + (size_t)p.x * NCLSP + fl * 2);
        a0 += v * b2f((ushort_t)(h & 0xffff));
        a1 += v * b2f((ushort_t)(h >> 16));
    }
    if (fl < NCLS / 2) {
        float2 o;
        o.x = a0 + b2[fl * 2];
        o.y = a1 + b2[fl * 2 + 1];
        *(float2*)(out + (size_t)r * NCLS + fl * 2) = o;
    }
}

// ---------------- launch ----------------

static inline size_t align256(size_t x) { return (x + 255) & ~(size_t)255; }

extern "C" void kernel_launch(void* const* d_in, const int* in_sizes, int n_in,
                              void* d_out, int out_size, void* d_ws, size_t ws_size,
                              hipStream_t stream) {
    const float* x        = (const float*)d_in[0];
    const float* W1       = (const float*)d_in[1];
    const float* b1       = (const float*)d_in[2];
    const float* W2       = (const float*)d_in[3];
    const float* b2       = (const float*)d_in[4];
    const int*   edge_row = (const int*)d_in[5];
    const int*   edge_col = (const int*)d_in[6];
    const float* edge_val = (const float*)d_in[7];
    float* out = (float*)d_out;

    int N = in_sizes[0] / NFEATS;  // 100000
    int E = in_sizes[5];           // 1700000

    char* w = (char*)d_ws;
    size_t off = 0;
    ushort_t* H1   = (ushort_t*)(w + off); off += align256((size_t)N * NHIDS * 2);
    ushort_t* AGG  = (ushort_t*)(w + off); off += align256((size_t)N * NHIDS * 2);
    ushort_t* H2   = (ushort_t*)(w + off); off += align256((size_t)N * NCLSP * 2);
    ushort_t* W1t  = (ushort_t*)(w + off); off += align256((size_t)NHIDS * NFEATS * 2);
    int*      row_ptr = (int*)(w + off); off += align256((size_t)(N + 1) * 4);
    int*      cnt     = (int*)(w + off); off += align256((size_t)N * 4);
    int2*     cv      = (int2*)(w + off); off += align256((size_t)E * 8);

    // CSR build + weight conversion
    hipMemsetAsync(cnt, 0, (size_t)N * 4, stream);
    hist_kernel<<<(E + 255) / 256, 256, 0, stream>>>(edge_row, cnt, E);
    convert_w1<<<(NFEATS * NHIDS) / 256, 256, 0, stream>>>(W1, W1t);
    scan_kernel<<<1, SCAN_T, 0, stream>>>(cnt, row_ptr, N);
    scatter_kernel<<<(E + 255) / 256, 256, 0, stream>>>(edge_row, edge_col, edge_val,
                                                        row_ptr, cnt, cv, E);

    // layer 1
    gemm1_kernel<<<(N + G1_BM - 1) / G1_BM, 256, 0, stream>>>(x, W1t, H1, N);
    spmm1_kernel<<<(N + 3) / 4, 256, 0, stream>>>(row_ptr, cv, H1, b1, AGG, N);

    // layer 2
    gemm2_kernel<<<(N + 255) / 256, 256, 0, stream>>>(AGG, W2, H2, N);
    spmm2_kernel<<<(N + 7) / 8, 256, 0, stream>>>(row_ptr, cv, H2, b2, out, N);
}

// Round 4
// 942.897 us; speedup vs baseline: 1.6332x; 1.2308x over previous
//
#include <hip/hip_runtime.h>
#include <hip/hip_bf16.h>

// GCN forward: out = spmm(A, relu(spmm(A, x@W1)+b1) @ W2) + b2
// bf16 intermediate pipeline: GEMM1 via MFMA bf16, H1/AGG/H2 stored bf16.
// R4: replace single-block scan (230 us, 0.15% occupancy) with 3-dispatch
// device-wide scan (partial sums -> scan sums -> finalize).

#define NFEATS 512
#define NHIDS  256
#define NCLS   40
#define NCLSP  64   // H2 padded feature stride (one 128B line per row)

typedef unsigned short ushort_t;
typedef unsigned int uint_t;
typedef __attribute__((ext_vector_type(8))) short frag8;   // 8 bf16 = 16 B
typedef __attribute__((ext_vector_type(4))) float floatx4;

__device__ __forceinline__ ushort_t f2b(float f) {
    uint_t u = __float_as_uint(f);
    uint_t r = (u + 0x7fffu + ((u >> 16) & 1u)) >> 16;   // RNE
    return (ushort_t)r;
}
__device__ __forceinline__ float b2f(ushort_t b) {
    return __uint_as_float((uint_t)b << 16);
}

// ---------------- CSR build ----------------

__global__ void hist_kernel(const int* __restrict__ row, int* __restrict__ cnt, int E) {
    int e = blockIdx.x * blockDim.x + threadIdx.x;
    if (e < E) atomicAdd(&cnt[row[e]], 1);
}

// device-wide exclusive scan of cnt[N] -> row_ptr[N+1]; zeroes cnt.
#define PS_T 256
#define PS_C 4
#define PS_CHUNK (PS_T * PS_C)   // 1024 elements per block

__global__ __launch_bounds__(PS_T) void scan_partial_kernel(const int* __restrict__ cnt,
                                                            int* __restrict__ blockSums, int N) {
    __shared__ int sm[PS_T];
    int t = threadIdx.x;
    int base = blockIdx.x * PS_CHUNK + t * PS_C;
    int s = 0;
    if (base + PS_C <= N) {
        int4 v = *(const int4*)(cnt + base);
        s = v.x + v.y + v.z + v.w;
    } else {
        for (int i = 0; i < PS_C; i++) if (base + i < N) s += cnt[base + i];
    }
    sm[t] = s;
    __syncthreads();
    for (int off = PS_T / 2; off > 0; off >>= 1) {
        if (t < off) sm[t] += sm[t + off];
        __syncthreads();
    }
    if (t == 0) blockSums[blockIdx.x] = sm[0];
}

#define SS_T 128   // must be >= number of scan blocks (98)
__global__ __launch_bounds__(SS_T) void scan_sums_kernel(int* __restrict__ blockSums, int B) {
    __shared__ int sm[SS_T];
    int t = threadIdx.x;
    int v = (t < B) ? blockSums[t] : 0;
    sm[t] = v;
    __syncthreads();
    for (int off = 1; off < SS_T; off <<= 1) {
        int x = (t >= off) ? sm[t - off] : 0;
        __syncthreads();
        sm[t] += x;
        __syncthreads();
    }
    if (t < B) blockSums[t] = sm[t] - v;   // exclusive
}

__global__ __launch_bounds__(PS_T) void scan_finalize_kernel(int* __restrict__ cnt,
                                                             const int* __restrict__ blockSums,
                                                             int* __restrict__ row_ptr, int N, int E) {
    __shared__ int sm[PS_T];
    int t = threadIdx.x;
    int base = blockIdx.x * PS_CHUNK + t * PS_C;
    int vals[PS_C];
    int s = 0;
#pragma unroll
    for (int i = 0; i < PS_C; i++) {
        int idx = base + i;
        vals[i] = (idx < N) ? cnt[idx] : 0;
        s += vals[i];
    }
    sm[t] = s;
    __syncthreads();
    for (int off = 1; off < PS_T; off <<= 1) {
        int x = (t >= off) ? sm[t - off] : 0;
        __syncthreads();
        sm[t] += x;
        __syncthreads();
    }
    int run = blockSums[blockIdx.x] + sm[t] - s;   // exclusive prefix for this thread
#pragma unroll
    for (int i = 0; i < PS_C; i++) {
        int idx = base + i;
        if (idx < N) {
            row_ptr[idx] = run;
            run += vals[i];
            cnt[idx] = 0;   // reuse as fill counter in scatter
        }
    }
    if (blockIdx.x == 0 && t == 0) row_ptr[N] = E;
}

__global__ void scatter_kernel(const int* __restrict__ row, const int* __restrict__ col,
                               const float* __restrict__ val, const int* __restrict__ row_ptr,
                               int* __restrict__ fill, int2* __restrict__ cv, int E) {
    int e = blockIdx.x * blockDim.x + threadIdx.x;
    if (e < E) {
        int r = row[e];
        int p = row_ptr[r] + atomicAdd(&fill[r], 1);
        cv[p] = make_int2(col[e], __float_as_int(val[e]));
    }
}

// ---------------- W1 convert+transpose: [512][256] f32 -> [256][512] bf16 ----------------

__global__ void convert_w1(const float* __restrict__ W1, ushort_t* __restrict__ W1t) {
    int idx = blockIdx.x * 256 + threadIdx.x;   // 131072 total
    int k = idx >> 8, n = idx & 255;
    W1t[n * 512 + k] = f2b(W1[idx]);
}

// ---------------- GEMM1: H1 = bf16(x @ W1)  via MFMA ----------------
// tile 64(M) x 256(N), BK=32, 256 threads = 4 waves; wave w covers n = w*64..w*64+63.

#define G1_BM 64
#define G1_BN 256
#define G1_BK 32
#define LDK   40   // padded K-stride (elements); 80 B, 16B-aligned

__global__ __launch_bounds__(256) void gemm1_kernel(const float* __restrict__ A,
                                                    const ushort_t* __restrict__ Bt,
                                                    ushort_t* __restrict__ H1, int M) {
    __shared__ ushort_t As[G1_BM * LDK];   // 5120 B
    __shared__ ushort_t Bs[G1_BN * LDK];   // 20480 B
    int tid  = threadIdx.x;
    int wave = tid >> 6, lane = tid & 63;
    int quad = lane >> 4, ln = lane & 15;
    int m0 = blockIdx.x * G1_BM;

    floatx4 acc[4][4] = {};

    for (int k0 = 0; k0 < NFEATS; k0 += G1_BK) {
#pragma unroll
        for (int i = 0; i < 2; i++) {
            int idx = i * 256 + tid;
            int row = idx >> 3;
            int c4  = idx & 7;
            float4 v = make_float4(0.f, 0.f, 0.f, 0.f);
            int gr = m0 + row;
            if (gr < M) v = *(const float4*)(A + (size_t)gr * NFEATS + k0 + c4 * 4);
            ushort4 b;
            b.x = f2b(v.x); b.y = f2b(v.y); b.z = f2b(v.z); b.w = f2b(v.w);
            *(ushort4*)&As[row * LDK + c4 * 4] = b;
        }
#pragma unroll
        for (int i = 0; i < 4; i++) {
            int idx = i * 256 + tid;
            int n  = idx >> 2;
            int k8 = idx & 3;
            uint4 v = *(const uint4*)(Bt + (size_t)n * 512 + k0 + k8 * 8);
            *(uint4*)&Bs[n * LDK + k8 * 8] = v;
        }
        __syncthreads();
        frag8 af[4], bf[4];
#pragma unroll
        for (int t = 0; t < 4; t++)
            af[t] = *(const frag8*)&As[(t * 16 + ln) * LDK + quad * 8];
#pragma unroll
        for (int t = 0; t < 4; t++)
            bf[t] = *(const frag8*)&Bs[(wave * 64 + t * 16 + ln) * LDK + quad * 8];
#pragma unroll
        for (int mt = 0; mt < 4; mt++)
#pragma unroll
            for (int nt = 0; nt < 4; nt++)
                acc[mt][nt] = __builtin_amdgcn_mfma_f32_16x16x32_bf16(af[mt], bf[nt], acc[mt][nt], 0, 0, 0);
        __syncthreads();
    }
#pragma unroll
    for (int mt = 0; mt < 4; mt++) {
#pragma unroll
        for (int i = 0; i < 4; i++) {
            int m = m0 + mt * 16 + quad * 4 + i;
            if (m < M) {
#pragma unroll
                for (int nt = 0; nt < 4; nt++) {
                    H1[(size_t)m * NHIDS + wave * 64 + nt * 16 + ln] = f2b(acc[mt][nt][i]);
                }
            }
        }
    }
}

// ---------------- SpMM1: AGG = bf16(relu(A_hat @ H1 + b1)), F=256 ----------------

__global__ __launch_bounds__(256) void spmm1_kernel(const int* __restrict__ row_ptr,
                                                    const int2* __restrict__ cv,
                                                    const ushort_t* __restrict__ H1,
                                                    const float* __restrict__ b1,
                                                    ushort_t* __restrict__ AGG, int N) {
    int wave = threadIdx.x >> 6, lane = threadIdx.x & 63;
    int r = blockIdx.x * 4 + wave;
    if (r >= N) return;
    int s = row_ptr[r], e = row_ptr[r + 1];
    float a0 = 0.f, a1 = 0.f, a2 = 0.f, a3 = 0.f;
    int j = s;
    for (; j + 1 < e; j += 2) {
        int2 p0 = cv[j];
        int2 p1 = cv[j + 1];
        ushort4 h0 = *(const ushort4*)(H1 + (size_t)p0.x * NHIDS + lane * 4);
        ushort4 h1 = *(const ushort4*)(H1 + (size_t)p1.x * NHIDS + lane * 4);
        float v0 = __int_as_float(p0.y), v1 = __int_as_float(p1.y);
        a0 += v0 * b2f(h0.x); a1 += v0 * b2f(h0.y); a2 += v0 * b2f(h0.z); a3 += v0 * b2f(h0.w);
        a0 += v1 * b2f(h1.x); a1 += v1 * b2f(h1.y); a2 += v1 * b2f(h1.z); a3 += v1 * b2f(h1.w);
    }
    if (j < e) {
        int2 p0 = cv[j];
        ushort4 h0 = *(const ushort4*)(H1 + (size_t)p0.x * NHIDS + lane * 4);
        float v0 = __int_as_float(p0.y);
        a0 += v0 * b2f(h0.x); a1 += v0 * b2f(h0.y); a2 += v0 * b2f(h0.z); a3 += v0 * b2f(h0.w);
    }
    float4 bb = *(const float4*)(b1 + lane * 4);
    a0 += bb.x; a1 += bb.y; a2 += bb.z; a3 += bb.w;
    ushort4 o;
    o.x = f2b(a0 > 0.f ? a0 : 0.f);
    o.y = f2b(a1 > 0.f ? a1 : 0.f);
    o.z = f2b(a2 > 0.f ? a2 : 0.f);
    o.w = f2b(a3 > 0.f ? a3 : 0.f);
    *(ushort4*)&AGG[(size_t)r * NHIDS + lane * 4] = o;
}

// ---------------- GEMM2: H2 = bf16(AGG @ W2), padded to 64 cols ----------------

__global__ __launch_bounds__(256) void gemm2_kernel(const ushort_t* __restrict__ AGG,
                                                    const float* __restrict__ W2,
                                                    ushort_t* __restrict__ H2, int M) {
    int row = blockIdx.x * 256 + threadIdx.x;
    if (row >= M) return;
    const ushort_t* a = AGG + (size_t)row * NHIDS;
    float acc[NCLS] = {};
    for (int k0 = 0; k0 < NHIDS; k0 += 8) {
        uint4 av = *(const uint4*)(a + k0);
        float f0 = b2f((ushort_t)(av.x & 0xffff)), f1 = b2f((ushort_t)(av.x >> 16));
        float f2 = b2f((ushort_t)(av.y & 0xffff)), f3 = b2f((ushort_t)(av.y >> 16));
        float f4 = b2f((ushort_t)(av.z & 0xffff)), f5 = b2f((ushort_t)(av.z >> 16));
        float f6 = b2f((ushort_t)(av.w & 0xffff)), f7 = b2f((ushort_t)(av.w >> 16));
#pragma unroll
        for (int jj = 0; jj < NCLS; jj++) {
            acc[jj] += f0 * W2[(k0 + 0) * NCLS + jj];
            acc[jj] += f1 * W2[(k0 + 1) * NCLS + jj];
            acc[jj] += f2 * W2[(k0 + 2) * NCLS + jj];
            acc[jj] += f3 * W2[(k0 + 3) * NCLS + jj];
            acc[jj] += f4 * W2[(k0 + 4) * NCLS + jj];
            acc[jj] += f5 * W2[(k0 + 5) * NCLS + jj];
            acc[jj] += f6 * W2[(k0 + 6) * NCLS + jj];
            acc[jj] += f7 * W2[(k0 + 7) * NCLS + jj];
        }
    }
    uint_t packed[NCLSP / 2];
#pragma unroll
    for (int jj = 0; jj < NCLS / 2; jj++)
        packed[jj] = (uint_t)f2b(acc[2 * jj]) | ((uint_t)f2b(acc[2 * jj + 1]) << 16);
#pragma unroll
    for (int jj = NCLS / 2; jj < NCLSP / 2; jj++) packed[jj] = 0;
    uint_t* o = (uint_t*)(H2 + (size_t)row * NCLSP);
#pragma unroll
    for (int q = 0; q < NCLSP / 8; q++)
        *(uint4*)(o + q * 4) = make_uint4(packed[q * 4], packed[q * 4 + 1], packed[q * 4 + 2], packed[q * 4 + 3]);
}

// ---------------- SpMM2: out = A_hat @ H2 + b2, F=40 (padded reads of 64) ----------------

__global__ __launch_bounds__(256) void spmm2_kernel(const int* __restrict__ row_ptr,
                                                    const int2* __restrict__ cv,
                                                    const ushort_t* __restrict__ H2,
                                                    const float* __restrict__ b2,
                                                    float* __restrict__ out, int N) {
    int wave = threadIdx.x >> 6, lane = threadIdx.x & 63;
    int half = lane >> 5, fl = lane & 31;
    int r = blockIdx.x * 8 + wave * 2 + half;
    if (r >= N) return;
    int s = row_ptr[r], e = row_ptr[r + 1];
    float a0 = 0.f, a1 = 0.f;
    for (int j = s; j < e; j++) {
        int2 p = cv[j];
        float v = __int_as_float(p.y);
        uint_t h = *(const uint_t*)(H2 + (size_t)p.x * NCLSP + fl * 2);
        a0 += v * b2f((ushort_t)(h & 0xffff));
        a1 += v * b2f((ushort_t)(h >> 16));
    }
    if (fl < NCLS / 2) {
        float2 o;
        o.x = a0 + b2[fl * 2];
        o.y = a1 + b2[fl * 2 + 1];
        *(float2*)(out + (size_t)r * NCLS + fl * 2) = o;
    }
}

// ---------------- launch ----------------

static inline size_t align256(size_t x) { return (x + 255) & ~(size_t)255; }

extern "C" void kernel_launch(void* const* d_in, const int* in_sizes, int n_in,
                              void* d_out, int out_size, void* d_ws, size_t ws_size,
                              hipStream_t stream) {
    const float* x        = (const float*)d_in[0];
    const float* W1       = (const float*)d_in[1];
    const float* b1       = (const float*)d_in[2];
    const float* W2       = (const float*)d_in[3];
    const float* b2       = (const float*)d_in[4];
    const int*   edge_row = (const int*)d_in[5];
    const int*   edge_col = (const int*)d_in[6];
    const float* edge_val = (const float*)d_in[7];
    float* out = (float*)d_out;

    int N = in_sizes[0] / NFEATS;  // 100000
    int E = in_sizes[5];           // 1700000

    char* w = (char*)d_ws;
    size_t off = 0;
    ushort_t* H1   = (ushort_t*)(w + off); off += align256((size_t)N * NHIDS * 2);
    ushort_t* AGG  = (ushort_t*)(w + off); off += align256((size_t)N * NHIDS * 2);
    ushort_t* H2   = (ushort_t*)(w + off); off += align256((size_t)N * NCLSP * 2);
    ushort_t* W1t  = (ushort_t*)(w + off); off += align256((size_t)NHIDS * NFEATS * 2);
    int*      row_ptr = (int*)(w + off); off += align256((size_t)(N + 1) * 4);
    int*      cnt     = (int*)(w + off); off += align256((size_t)N * 4);
    int*      blockSums = (int*)(w + off); off += align256((size_t)SS_T * 4);
    int2*     cv      = (int2*)(w + off); off += align256((size_t)E * 8);

    int scanB = (N + PS_CHUNK - 1) / PS_CHUNK;   // 98 for N=100000 (must be <= SS_T)

    // CSR build + weight conversion
    hipMemsetAsync(cnt, 0, (size_t)N * 4, stream);
    hist_kernel<<<(E + 255) / 256, 256, 0, stream>>>(edge_row, cnt, E);
    convert_w1<<<(NFEATS * NHIDS) / 256, 256, 0, stream>>>(W1, W1t);
    scan_partial_kernel<<<scanB, PS_T, 0, stream>>>(cnt, blockSums, N);
    scan_sums_kernel<<<1, SS_T, 0, stream>>>(blockSums, scanB);
    scan_finalize_kernel<<<scanB, PS_T, 0, stream>>>(cnt, blockSums, row_ptr, N, E);
    scatter_kernel<<<(E + 255) / 256, 256, 0, stream>>>(edge_row, edge_col, edge_val,
                                                        row_ptr, cnt, cv, E);

    // layer 1
    gemm1_kernel<<<(N + G1_BM - 1) / G1_BM, 256, 0, stream>>>(x, W1t, H1, N);
    spmm1_kernel<<<(N + 3) / 4, 256, 0, stream>>>(row_ptr, cv, H1, b1, AGG, N);

    // layer 2
    gemm2_kernel<<<(N + 255) / 256, 256, 0, stream>>>(AGG, W2, H2, N);
    spmm2_kernel<<<(N + 7) / 8, 256, 0, stream>>>(row_ptr, cv, H2, b2, out, N);
}

// Round 5
// 746.743 us; speedup vs baseline: 2.0622x; 1.2627x over previous
//
#include <hip/hip_runtime.h>
#include <hip/hip_bf16.h>

// GCN forward: out = spmm(A, relu(spmm(A, x@W1)+b1) @ W2) + b2
// bf16 intermediate pipeline: GEMM1 + GEMM2 via MFMA bf16, H1/AGG/H2 stored bf16.
// R5: gemm2 was latency-bound (223us, VALUBusy 10%, occ 18% — scalar W2 loads,
// 391 blocks). Rewritten as barrier-free MFMA GEMM over W2t bf16 (64x256, padded).

#define NFEATS 512
#define NHIDS  256
#define NCLS   40
#define NCLSP  64   // H2 padded feature stride (one 128B line per row)

typedef unsigned short ushort_t;
typedef unsigned int uint_t;
typedef __attribute__((ext_vector_type(8))) short frag8;   // 8 bf16 = 16 B
typedef __attribute__((ext_vector_type(4))) float floatx4;

__device__ __forceinline__ ushort_t f2b(float f) {
    uint_t u = __float_as_uint(f);
    uint_t r = (u + 0x7fffu + ((u >> 16) & 1u)) >> 16;   // RNE
    return (ushort_t)r;
}
__device__ __forceinline__ float b2f(ushort_t b) {
    return __uint_as_float((uint_t)b << 16);
}

// ---------------- CSR build ----------------

__global__ void hist_kernel(const int* __restrict__ row, int* __restrict__ cnt, int E) {
    int e = blockIdx.x * blockDim.x + threadIdx.x;
    if (e < E) atomicAdd(&cnt[row[e]], 1);
}

// device-wide exclusive scan of cnt[N] -> row_ptr[N+1]; zeroes cnt.
#define PS_T 256
#define PS_C 4
#define PS_CHUNK (PS_T * PS_C)   // 1024 elements per block

__global__ __launch_bounds__(PS_T) void scan_partial_kernel(const int* __restrict__ cnt,
                                                            int* __restrict__ blockSums, int N) {
    __shared__ int sm[PS_T];
    int t = threadIdx.x;
    int base = blockIdx.x * PS_CHUNK + t * PS_C;
    int s = 0;
    if (base + PS_C <= N) {
        int4 v = *(const int4*)(cnt + base);
        s = v.x + v.y + v.z + v.w;
    } else {
        for (int i = 0; i < PS_C; i++) if (base + i < N) s += cnt[base + i];
    }
    sm[t] = s;
    __syncthreads();
    for (int off = PS_T / 2; off > 0; off >>= 1) {
        if (t < off) sm[t] += sm[t + off];
        __syncthreads();
    }
    if (t == 0) blockSums[blockIdx.x] = sm[0];
}

#define SS_T 128   // must be >= number of scan blocks (98)
__global__ __launch_bounds__(SS_T) void scan_sums_kernel(int* __restrict__ blockSums, int B) {
    __shared__ int sm[SS_T];
    int t = threadIdx.x;
    int v = (t < B) ? blockSums[t] : 0;
    sm[t] = v;
    __syncthreads();
    for (int off = 1; off < SS_T; off <<= 1) {
        int x = (t >= off) ? sm[t - off] : 0;
        __syncthreads();
        sm[t] += x;
        __syncthreads();
    }
    if (t < B) blockSums[t] = sm[t] - v;   // exclusive
}

__global__ __launch_bounds__(PS_T) void scan_finalize_kernel(int* __restrict__ cnt,
                                                             const int* __restrict__ blockSums,
                                                             int* __restrict__ row_ptr, int N, int E) {
    __shared__ int sm[PS_T];
    int t = threadIdx.x;
    int base = blockIdx.x * PS_CHUNK + t * PS_C;
    int vals[PS_C];
    int s = 0;
#pragma unroll
    for (int i = 0; i < PS_C; i++) {
        int idx = base + i;
        vals[i] = (idx < N) ? cnt[idx] : 0;
        s += vals[i];
    }
    sm[t] = s;
    __syncthreads();
    for (int off = 1; off < PS_T; off <<= 1) {
        int x = (t >= off) ? sm[t - off] : 0;
        __syncthreads();
        sm[t] += x;
        __syncthreads();
    }
    int run = blockSums[blockIdx.x] + sm[t] - s;   // exclusive prefix for this thread
#pragma unroll
    for (int i = 0; i < PS_C; i++) {
        int idx = base + i;
        if (idx < N) {
            row_ptr[idx] = run;
            run += vals[i];
            cnt[idx] = 0;   // reuse as fill counter in scatter
        }
    }
    if (blockIdx.x == 0 && t == 0) row_ptr[N] = E;
}

__global__ void scatter_kernel(const int* __restrict__ row, const int* __restrict__ col,
                               const float* __restrict__ val, const int* __restrict__ row_ptr,
                               int* __restrict__ fill, int2* __restrict__ cv, int E) {
    int e = blockIdx.x * blockDim.x + threadIdx.x;
    if (e < E) {
        int r = row[e];
        int p = row_ptr[r] + atomicAdd(&fill[r], 1);
        cv[p] = make_int2(col[e], __float_as_int(val[e]));
    }
}

// ---------------- weight conversions ----------------

// W1 [512][256] f32 -> W1t [256][512] bf16 (n-major)
__global__ void convert_w1(const float* __restrict__ W1, ushort_t* __restrict__ W1t) {
    int idx = blockIdx.x * 256 + threadIdx.x;   // 131072 total
    int k = idx >> 8, n = idx & 255;
    W1t[n * 512 + k] = f2b(W1[idx]);
}

// W2 [256][40] f32 -> W2t [64][256] bf16 (n-major, rows 40..63 zero)
__global__ void convert_w2(const float* __restrict__ W2, ushort_t* __restrict__ W2t) {
    int idx = blockIdx.x * 256 + threadIdx.x;   // 16384 total
    int n = idx >> 8, k = idx & 255;
    W2t[idx] = (n < NCLS) ? f2b(W2[k * NCLS + n]) : (ushort_t)0;
}

// ---------------- GEMM1: H1 = bf16(x @ W1)  via MFMA ----------------
// tile 64(M) x 256(N), BK=32, 256 threads = 4 waves; wave w covers n = w*64..w*64+63.

#define G1_BM 64
#define G1_BN 256
#define G1_BK 32
#define LDK   40   // padded K-stride (elements); 80 B, 16B-aligned

__global__ __launch_bounds__(256) void gemm1_kernel(const float* __restrict__ A,
                                                    const ushort_t* __restrict__ Bt,
                                                    ushort_t* __restrict__ H1, int M) {
    __shared__ ushort_t As[G1_BM * LDK];   // 5120 B
    __shared__ ushort_t Bs[G1_BN * LDK];   // 20480 B
    int tid  = threadIdx.x;
    int wave = tid >> 6, lane = tid & 63;
    int quad = lane >> 4, ln = lane & 15;
    int m0 = blockIdx.x * G1_BM;

    floatx4 acc[4][4] = {};

    for (int k0 = 0; k0 < NFEATS; k0 += G1_BK) {
#pragma unroll
        for (int i = 0; i < 2; i++) {
            int idx = i * 256 + tid;
            int row = idx >> 3;
            int c4  = idx & 7;
            float4 v = make_float4(0.f, 0.f, 0.f, 0.f);
            int gr = m0 + row;
            if (gr < M) v = *(const float4*)(A + (size_t)gr * NFEATS + k0 + c4 * 4);
            ushort4 b;
            b.x = f2b(v.x); b.y = f2b(v.y); b.z = f2b(v.z); b.w = f2b(v.w);
            *(ushort4*)&As[row * LDK + c4 * 4] = b;
        }
#pragma unroll
        for (int i = 0; i < 4; i++) {
            int idx = i * 256 + tid;
            int n  = idx >> 2;
            int k8 = idx & 3;
            uint4 v = *(const uint4*)(Bt + (size_t)n * 512 + k0 + k8 * 8);
            *(uint4*)&Bs[n * LDK + k8 * 8] = v;
        }
        __syncthreads();
        frag8 af[4], bf[4];
#pragma unroll
        for (int t = 0; t < 4; t++)
            af[t] = *(const frag8*)&As[(t * 16 + ln) * LDK + quad * 8];
#pragma unroll
        for (int t = 0; t < 4; t++)
            bf[t] = *(const frag8*)&Bs[(wave * 64 + t * 16 + ln) * LDK + quad * 8];
#pragma unroll
        for (int mt = 0; mt < 4; mt++)
#pragma unroll
            for (int nt = 0; nt < 4; nt++)
                acc[mt][nt] = __builtin_amdgcn_mfma_f32_16x16x32_bf16(af[mt], bf[nt], acc[mt][nt], 0, 0, 0);
        __syncthreads();
    }
#pragma unroll
    for (int mt = 0; mt < 4; mt++) {
#pragma unroll
        for (int i = 0; i < 4; i++) {
            int m = m0 + mt * 16 + quad * 4 + i;
            if (m < M) {
#pragma unroll
                for (int nt = 0; nt < 4; nt++) {
                    H1[(size_t)m * NHIDS + wave * 64 + nt * 16 + ln] = f2b(acc[mt][nt][i]);
                }
            }
        }
    }
}

// ---------------- SpMM1: AGG = bf16(relu(A_hat @ H1 + b1)), F=256 ----------------

__global__ __launch_bounds__(256) void spmm1_kernel(const int* __restrict__ row_ptr,
                                                    const int2* __restrict__ cv,
                                                    const ushort_t* __restrict__ H1,
                                                    const float* __restrict__ b1,
                                                    ushort_t* __restrict__ AGG, int N) {
    int wave = threadIdx.x >> 6, lane = threadIdx.x & 63;
    int r = blockIdx.x * 4 + wave;
    if (r >= N) return;
    int s = row_ptr[r], e = row_ptr[r + 1];
    float a0 = 0.f, a1 = 0.f, a2 = 0.f, a3 = 0.f;
    int j = s;
    for (; j + 1 < e; j += 2) {
        int2 p0 = cv[j];
        int2 p1 = cv[j + 1];
        ushort4 h0 = *(const ushort4*)(H1 + (size_t)p0.x * NHIDS + lane * 4);
        ushort4 h1 = *(const ushort4*)(H1 + (size_t)p1.x * NHIDS + lane * 4);
        float v0 = __int_as_float(p0.y), v1 = __int_as_float(p1.y);
        a0 += v0 * b2f(h0.x); a1 += v0 * b2f(h0.y); a2 += v0 * b2f(h0.z); a3 += v0 * b2f(h0.w);
        a0 += v1 * b2f(h1.x); a1 += v1 * b2f(h1.y); a2 += v1 * b2f(h1.z); a3 += v1 * b2f(h1.w);
    }
    if (j < e) {
        int2 p0 = cv[j];
        ushort4 h0 = *(const ushort4*)(H1 + (size_t)p0.x * NHIDS + lane * 4);
        float v0 = __int_as_float(p0.y);
        a0 += v0 * b2f(h0.x); a1 += v0 * b2f(h0.y); a2 += v0 * b2f(h0.z); a3 += v0 * b2f(h0.w);
    }
    float4 bb = *(const float4*)(b1 + lane * 4);
    a0 += bb.x; a1 += bb.y; a2 += bb.z; a3 += bb.w;
    ushort4 o;
    o.x = f2b(a0 > 0.f ? a0 : 0.f);
    o.y = f2b(a1 > 0.f ? a1 : 0.f);
    o.z = f2b(a2 > 0.f ? a2 : 0.f);
    o.w = f2b(a3 > 0.f ? a3 : 0.f);
    *(ushort4*)&AGG[(size_t)r * NHIDS + lane * 4] = o;
}

// ---------------- GEMM2: H2 = bf16(AGG @ W2) via MFMA, padded to 64 cols ----------------
// 256 threads = 4 waves; block covers 256 rows (wave w: rows w*64..w*64+63).
// All 64 output cols per wave = 4 n-tiles; K=256 = 8 chunks of 32. No LDS, no barriers:
// A-frags direct from AGG (16B/lane), B-frags from W2t (32 KB, L1/L2-resident).

__global__ __launch_bounds__(256) void gemm2_kernel(const ushort_t* __restrict__ AGG,
                                                    const ushort_t* __restrict__ W2t,
                                                    ushort_t* __restrict__ H2, int M) {
    int tid  = threadIdx.x;
    int wave = tid >> 6, lane = tid & 63;
    int quad = lane >> 4, ln = lane & 15;
    int m0 = blockIdx.x * 256 + wave * 64;

    floatx4 acc[4][4] = {};
    frag8 zf = {};

#pragma unroll
    for (int k0 = 0; k0 < NHIDS; k0 += 32) {
        frag8 af[4], bf[4];
#pragma unroll
        for (int mt = 0; mt < 4; mt++) {
            int m = m0 + mt * 16 + ln;
            af[mt] = (m < M) ? *(const frag8*)(AGG + (size_t)m * NHIDS + k0 + quad * 8) : zf;
        }
#pragma unroll
        for (int nt = 0; nt < 4; nt++)
            bf[nt] = *(const frag8*)(W2t + (size_t)(nt * 16 + ln) * NHIDS + k0 + quad * 8);
#pragma unroll
        for (int mt = 0; mt < 4; mt++)
#pragma unroll
            for (int nt = 0; nt < 4; nt++)
                acc[mt][nt] = __builtin_amdgcn_mfma_f32_16x16x32_bf16(af[mt], bf[nt], acc[mt][nt], 0, 0, 0);
    }
    // C/D layout: col = ln, row = quad*4 + i
#pragma unroll
    for (int mt = 0; mt < 4; mt++) {
#pragma unroll
        for (int i = 0; i < 4; i++) {
            int m = m0 + mt * 16 + quad * 4 + i;
            if (m < M) {
#pragma unroll
                for (int nt = 0; nt < 4; nt++)
                    H2[(size_t)m * NCLSP + nt * 16 + ln] = f2b(acc[mt][nt][i]);
            }
        }
    }
}

// ---------------- SpMM2: out = A_hat @ H2 + b2, F=40 (padded reads of 64) ----------------

__global__ __launch_bounds__(256) void spmm2_kernel(const int* __restrict__ row_ptr,
                                                    const int2* __restrict__ cv,
                                                    const ushort_t* __restrict__ H2,
                                                    const float* __restrict__ b2,
                                                    float* __restrict__ out, int N) {
    int wave = threadIdx.x >> 6, lane = threadIdx.x & 63;
    int half = lane >> 5, fl = lane & 31;
    int r = blockIdx.x * 8 + wave * 2 + half;
    if (r >= N) return;
    int s = row_ptr[r], e = row_ptr[r + 1];
    float a0 = 0.f, a1 = 0.f;
    for (int j = s; j < e; j++) {
        int2 p = cv[j];
        float v = __int_as_float(p.y);
        uint_t h = *(const uint_t*)(H2 + (size_t)p.x * NCLSP + fl * 2);
        a0 += v * b2f((ushort_t)(h & 0xffff));
        a1 += v * b2f((ushort_t)(h >> 16));
    }
    if (fl < NCLS / 2) {
        float2 o;
        o.x = a0 + b2[fl * 2];
        o.y = a1 + b2[fl * 2 + 1];
        *(float2*)(out + (size_t)r * NCLS + fl * 2) = o;
    }
}

// ---------------- launch ----------------

static inline size_t align256(size_t x) { return (x + 255) & ~(size_t)255; }

extern "C" void kernel_launch(void* const* d_in, const int* in_sizes, int n_in,
                              void* d_out, int out_size, void* d_ws, size_t ws_size,
                              hipStream_t stream) {
    const float* x        = (const float*)d_in[0];
    const float* W1       = (const float*)d_in[1];
    const float* b1       = (const float*)d_in[2];
    const float* W2       = (const float*)d_in[3];
    const float* b2       = (const float*)d_in[4];
    const int*   edge_row = (const int*)d_in[5];
    const int*   edge_col = (const int*)d_in[6];
    const float* edge_val = (const float*)d_in[7];
    float* out = (float*)d_out;

    int N = in_sizes[0] / NFEATS;  // 100000
    int E = in_sizes[5];           // 1700000

    char* w = (char*)d_ws;
    size_t off = 0;
    ushort_t* H1   = (ushort_t*)(w + off); off += align256((size_t)N * NHIDS * 2);
    ushort_t* AGG  = (ushort_t*)(w + off); off += align256((size_t)N * NHIDS * 2);
    ushort_t* H2   = (ushort_t*)(w + off); off += align256((size_t)N * NCLSP * 2);
    ushort_t* W1t  = (ushort_t*)(w + off); off += align256((size_t)NHIDS * NFEATS * 2);
    ushort_t* W2t  = (ushort_t*)(w + off); off += align256((size_t)NCLSP * NHIDS * 2);
    int*      row_ptr = (int*)(w + off); off += align256((size_t)(N + 1) * 4);
    int*      cnt     = (int*)(w + off); off += align256((size_t)N * 4);
    int*      blockSums = (int*)(w + off); off += align256((size_t)SS_T * 4);
    int2*     cv      = (int2*)(w + off); off += align256((size_t)E * 8);

    int scanB = (N + PS_CHUNK - 1) / PS_CHUNK;   // 98 for N=100000 (must be <= SS_T)

    // CSR build + weight conversion
    hipMemsetAsync(cnt, 0, (size_t)N * 4, stream);
    hist_kernel<<<(E + 255) / 256, 256, 0, stream>>>(edge_row, cnt, E);
    convert_w1<<<(NFEATS * NHIDS) / 256, 256, 0, stream>>>(W1, W1t);
    convert_w2<<<(NCLSP * NHIDS) / 256, 256, 0, stream>>>(W2, W2t);
    scan_partial_kernel<<<scanB, PS_T, 0, stream>>>(cnt, blockSums, N);
    scan_sums_kernel<<<1, SS_T, 0, stream>>>(blockSums, scanB);
    scan_finalize_kernel<<<scanB, PS_T, 0, stream>>>(cnt, blockSums, row_ptr, N, E);
    scatter_kernel<<<(E + 255) / 256, 256, 0, stream>>>(edge_row, edge_col, edge_val,
                                                        row_ptr, cnt, cv, E);

    // layer 1
    gemm1_kernel<<<(N + G1_BM - 1) / G1_BM, 256, 0, stream>>>(x, W1t, H1, N);
    spmm1_kernel<<<(N + 3) / 4, 256, 0, stream>>>(row_ptr, cv, H1, b1, AGG, N);

    // layer 2
    gemm2_kernel<<<(N + 255) / 256, 256, 0, stream>>>(AGG, W2t, H2, N);
    spmm2_kernel<<<(N + 7) / 8, 256, 0, stream>>>(row_ptr, cv, H2, b2, out, N);
}